// Round 11
// baseline (199.311 us; speedup 1.0000x reference)
//
#include <hip/hip_runtime.h>

// PINN fused: u, du/dx0, d2u/dx0^2 of tanh-MLP (2->256->256->256->1), fp32 in/out.
// Round 11 (= round 10 resubmitted; previous round hit a GPU-broker timeout).
// TWO-TILE software pipeline: two 16-sample tiles skewed by one stage so every
// k-loop (MFMA) carries the other tile's tanh-epilogue / layer-1 (VALU) in the
// same instruction stream -> both pipes fed within each wave.
//   - 16x16x32_f16 MFMA: D rows = 4 consecutive units, acc = 4 regs/tile-stream
//   - W2/W3 fragments cached in 64 VGPRs across the two stages using them
//   - LDS 2 x 25.3 KB -> 3 blocks/CU; psum arrays aliased onto dead bufs
//   - pkrtz packed f32->f16 conversions; fp16 hi-only weights+activations

#define HID 256
#define LDK 264   // f16 row stride: 528 B = multiple of 16 (b128-aligned rows)

typedef _Float16 half8  __attribute__((ext_vector_type(8)));
typedef __fp16   fp16x2 __attribute__((ext_vector_type(2)));
typedef float    f32x4  __attribute__((ext_vector_type(4)));

__device__ __forceinline__ float fast_tanh(float z) {
    const float e = __expf(2.0f * z);
#if __has_builtin(__builtin_amdgcn_rcpf)
    const float r = __builtin_amdgcn_rcpf(e + 1.0f);
#else
    const float r = 1.0f / (e + 1.0f);
#endif
    return fmaf(-2.0f, r, 1.0f);
}

__device__ __forceinline__ unsigned pkh(float lo, float hi) {
    union { fp16x2 h; unsigned u; } c;
    c.h = __builtin_amdgcn_cvt_pkrtz(lo, hi);
    return c.u;
}

#define MFMA16(a, b, c) __builtin_amdgcn_mfma_f32_16x16x32_f16((a), (b), (c), 0, 0, 0)

// Pack W2/W3 (fp32 [256][256], row=k, col=n) into 16x16x32 A-fragment order for
// W^T, fp16 hi-only: frag (tile nt, chunk kc, lane, j) =
//   W[kc*32 + (lane>>4)*8 + j][nt*16 + (lane&15)]
// ws layout (f16 elems): W2 @ 0, W3 @ 65536. idx = ((nt*8+kc)*64+lane)*8+j.
__global__ __launch_bounds__(256) void prep_w(const float* __restrict__ W2,
                                              const float* __restrict__ W3,
                                              _Float16* __restrict__ wsf) {
    const int t = blockIdx.x * 256 + threadIdx.x;     // 0..16383
    const float* __restrict__ W = (t >> 13) ? W3 : W2;
    _Float16* dst = wsf + (size_t)(t >> 13) * 65536;
    const int r    = t & 8191;
    const int nt   = r >> 9;           // unit tile 0..15
    const int kc   = (r >> 6) & 7;     // k chunk 0..7
    const int lane = r & 63;
    const int row  = kc * 32 + ((lane >> 4) << 3);    // k
    const int col  = nt * 16 + (lane & 15);           // unit (m)
    half8 vh;
    #pragma unroll
    for (int j = 0; j < 8; ++j)
        vh[j] = (_Float16)W[(size_t)(row + j) * HID + col];
    *(half8*)&dst[(size_t)r * 8] = vh;
}

__global__ __launch_bounds__(512) void pinn_mfma(
    const float* __restrict__ x,
    const float* __restrict__ W1, const float* __restrict__ b1,
    const float* __restrict__ b2, const float* __restrict__ b3,
    const float* __restrict__ W4, const float* __restrict__ b4,
    const _Float16* __restrict__ wsf,
    float* __restrict__ out, int B)
{
    __shared__ __align__(16) _Float16 bufA[3][16][LDK];   // 25,344 B
    __shared__ __align__(16) _Float16 bufB[3][16][LDK];   // 25,344 B
    float* const psumA = (float*)&bufA[0][0][0];          // aliased after bufA dead
    float* const psumB = (float*)&bufB[0][0][0];          // aliased after bufB dead

    const int tid  = threadIdx.x;
    const int lane = tid & 63;
    const int wave = tid >> 6;          // 0..7; owns unit tiles {2w, 2w+1}
    const int n    = lane & 15;         // sample within tile / D col / B-frag col
    const int q    = lane >> 4;         // 0..3
    const int q8   = q * 8;             // frag k offset
    const int sA   = blockIdx.x * 32;   // tile A first sample; tile B = sA+16
    const int u0   = wave * 32 + q * 8; // L1: this thread's 8-unit group

    #define WIDX(t_, c_) ((size_t)(((wave * 2 + (t_)) * 8 + (c_)) * 64 + lane) * 8)

    f32x4 accA[3][2], accB[3][2];
    half8 wc[2][8];                     // cached weight frags (W2 for s1/s2, W3 for s3/s4)

    // ---------------- s0: L1(A) ----------------
    {
        const float2 xv  = *(const float2*)&x[(size_t)(sA + n) * 2];
        const f32x4 wa0 = *(const f32x4*)&W1[u0];
        const f32x4 wa1 = *(const f32x4*)&W1[u0 + 4];
        const f32x4 wb0 = *(const f32x4*)&W1[HID + u0];
        const f32x4 wb1 = *(const f32x4*)&W1[HID + u0 + 4];
        const f32x4 bb0 = *(const f32x4*)&b1[u0];
        const f32x4 bb1 = *(const f32x4*)&b1[u0 + 4];
        unsigned pk[3][4];
        float pa = 0.f, pdv = 0.f, p2 = 0.f;
        #pragma unroll
        for (int j = 0; j < 8; ++j) {
            const float w0 = (j < 4) ? wa0[j & 3] : wa1[j & 3];
            const float w1v = (j < 4) ? wb0[j & 3] : wb1[j & 3];
            const float bb = (j < 4) ? bb0[j & 3] : bb1[j & 3];
            const float z  = fmaf(xv.x, w0, fmaf(xv.y, w1v, bb));
            const float a  = fast_tanh(z);
            const float sN = fmaf(-a, a, 1.0f);
            const float ad = sN * w0;
            const float add = -2.0f * a * ad * w0;
            if (j & 1) {
                pk[0][j >> 1] = pkh(pa, a);
                pk[1][j >> 1] = pkh(pdv, ad);
                pk[2][j >> 1] = pkh(p2, add);
            } else { pa = a; pdv = ad; p2 = add; }
        }
        #pragma unroll
        for (int s = 0; s < 3; ++s) {
            uint4 v; v.x = pk[s][0]; v.y = pk[s][1]; v.z = pk[s][2]; v.w = pk[s][3];
            *(uint4*)&bufA[s][n][u0] = v;
        }
    }
    __syncthreads();

    // ---------------- s1: L2k(A) [MFMA] + L1(B) [VALU] ----------------
    {
        #pragma unroll
        for (int c = 0; c < 8; ++c) {
            wc[0][c] = *(const half8*)&wsf[WIDX(0, c)];
            wc[1][c] = *(const half8*)&wsf[WIDX(1, c)];
        }
        #pragma unroll
        for (int s = 0; s < 3; ++s) {
            accA[s][0] = (f32x4){0.f, 0.f, 0.f, 0.f};
            accA[s][1] = (f32x4){0.f, 0.f, 0.f, 0.f};
        }
        const float2 xv  = *(const float2*)&x[(size_t)(sA + 16 + n) * 2];
        const f32x4 wa0 = *(const f32x4*)&W1[u0];
        const f32x4 wa1 = *(const f32x4*)&W1[u0 + 4];
        const f32x4 wb0 = *(const f32x4*)&W1[HID + u0];
        const f32x4 wb1 = *(const f32x4*)&W1[HID + u0 + 4];
        const f32x4 bb0 = *(const f32x4*)&b1[u0];
        const f32x4 bb1 = *(const f32x4*)&b1[u0 + 4];
        unsigned pk[3][4];
        float pa = 0.f, pdv = 0.f, p2 = 0.f;
        #pragma unroll
        for (int c = 0; c < 8; ++c) {
            const half8 f0 = *(const half8*)&bufA[0][n][c * 32 + q8];
            const half8 f1 = *(const half8*)&bufA[1][n][c * 32 + q8];
            const half8 f2 = *(const half8*)&bufA[2][n][c * 32 + q8];
            accA[0][0] = MFMA16(wc[0][c], f0, accA[0][0]);
            accA[1][0] = MFMA16(wc[0][c], f1, accA[1][0]);
            accA[2][0] = MFMA16(wc[0][c], f2, accA[2][0]);
            accA[0][1] = MFMA16(wc[1][c], f0, accA[0][1]);
            accA[1][1] = MFMA16(wc[1][c], f1, accA[1][1]);
            accA[2][1] = MFMA16(wc[1][c], f2, accA[2][1]);
            // L1(B), unit u0+c
            const float w0 = (c < 4) ? wa0[c & 3] : wa1[c & 3];
            const float w1v = (c < 4) ? wb0[c & 3] : wb1[c & 3];
            const float bb = (c < 4) ? bb0[c & 3] : bb1[c & 3];
            const float z  = fmaf(xv.x, w0, fmaf(xv.y, w1v, bb));
            const float a  = fast_tanh(z);
            const float sN = fmaf(-a, a, 1.0f);
            const float ad = sN * w0;
            const float add = -2.0f * a * ad * w0;
            if (c & 1) {
                pk[0][c >> 1] = pkh(pa, a);
                pk[1][c >> 1] = pkh(pdv, ad);
                pk[2][c >> 1] = pkh(p2, add);
            } else { pa = a; pdv = ad; p2 = add; }
        }
        #pragma unroll
        for (int s = 0; s < 3; ++s) {
            uint4 v; v.x = pk[s][0]; v.y = pk[s][1]; v.z = pk[s][2]; v.w = pk[s][3];
            *(uint4*)&bufB[s][n][u0] = v;
        }
    }
    __syncthreads();

    const f32x4 bb2a = *(const f32x4*)&b2[(wave * 2 + 0) * 16 + q * 4];
    const f32x4 bb2b = *(const f32x4*)&b2[(wave * 2 + 1) * 16 + q * 4];

    // ---------------- s2: L2e(A) [VALU] + L2k(B) [MFMA, W2 regs reused] ----------------
    {
        #pragma unroll
        for (int s = 0; s < 3; ++s) {
            accB[s][0] = (f32x4){0.f, 0.f, 0.f, 0.f};
            accB[s][1] = (f32x4){0.f, 0.f, 0.f, 0.f};
        }
        float pa = 0.f, pdv = 0.f, p2 = 0.f;
        #pragma unroll
        for (int c = 0; c < 8; ++c) {
            const half8 f0 = *(const half8*)&bufB[0][n][c * 32 + q8];
            const half8 f1 = *(const half8*)&bufB[1][n][c * 32 + q8];
            const half8 f2 = *(const half8*)&bufB[2][n][c * 32 + q8];
            accB[0][0] = MFMA16(wc[0][c], f0, accB[0][0]);
            accB[1][0] = MFMA16(wc[0][c], f1, accB[1][0]);
            accB[2][0] = MFMA16(wc[0][c], f2, accB[2][0]);
            accB[0][1] = MFMA16(wc[1][c], f0, accB[0][1]);
            accB[1][1] = MFMA16(wc[1][c], f1, accB[1][1]);
            accB[2][1] = MFMA16(wc[1][c], f2, accB[2][1]);
            // L2e(A), value index e=c: tile t=c>>2, D-reg r=c&3
            const int t = c >> 2, r = c & 3;
            const float z   = accA[0][t][r] + ((c < 4) ? bb2a[r] : bb2b[r]);
            const float a   = fast_tanh(z);
            const float sN  = fmaf(-a, a, 1.0f);
            const float zd  = accA[1][t][r];
            const float zdd = accA[2][t][r];
            const float ad  = sN * zd;
            const float tt  = a * ad * zd;
            const float add = fmaf(sN, zdd, -2.0f * tt);
            if (r & 1) {
                const int ub = (wave * 2 + t) * 16 + q * 4 + (r - 1);
                *(unsigned*)&bufA[0][n][ub] = pkh(pa, a);
                *(unsigned*)&bufA[1][n][ub] = pkh(pdv, ad);
                *(unsigned*)&bufA[2][n][ub] = pkh(p2, add);
            } else { pa = a; pdv = ad; p2 = add; }
        }
    }
    __syncthreads();

    // ---------------- s3: L3k(A) [MFMA, W3] + L2e(B) [VALU] ----------------
    {
        #pragma unroll
        for (int c = 0; c < 8; ++c) {
            wc[0][c] = *(const half8*)&wsf[65536 + WIDX(0, c)];
            wc[1][c] = *(const half8*)&wsf[65536 + WIDX(1, c)];
        }
        #pragma unroll
        for (int s = 0; s < 3; ++s) {
            accA[s][0] = (f32x4){0.f, 0.f, 0.f, 0.f};
            accA[s][1] = (f32x4){0.f, 0.f, 0.f, 0.f};
        }
        float pa = 0.f, pdv = 0.f, p2 = 0.f;
        #pragma unroll
        for (int c = 0; c < 8; ++c) {
            const half8 f0 = *(const half8*)&bufA[0][n][c * 32 + q8];
            const half8 f1 = *(const half8*)&bufA[1][n][c * 32 + q8];
            const half8 f2 = *(const half8*)&bufA[2][n][c * 32 + q8];
            accA[0][0] = MFMA16(wc[0][c], f0, accA[0][0]);
            accA[1][0] = MFMA16(wc[0][c], f1, accA[1][0]);
            accA[2][0] = MFMA16(wc[0][c], f2, accA[2][0]);
            accA[0][1] = MFMA16(wc[1][c], f0, accA[0][1]);
            accA[1][1] = MFMA16(wc[1][c], f1, accA[1][1]);
            accA[2][1] = MFMA16(wc[1][c], f2, accA[2][1]);
            // L2e(B), e=c
            const int t = c >> 2, r = c & 3;
            const float z   = accB[0][t][r] + ((c < 4) ? bb2a[r] : bb2b[r]);
            const float a   = fast_tanh(z);
            const float sN  = fmaf(-a, a, 1.0f);
            const float zd  = accB[1][t][r];
            const float zdd = accB[2][t][r];
            const float ad  = sN * zd;
            const float tt  = a * ad * zd;
            const float add = fmaf(sN, zdd, -2.0f * tt);
            if (r & 1) {
                const int ub = (wave * 2 + t) * 16 + q * 4 + (r - 1);
                *(unsigned*)&bufB[0][n][ub] = pkh(pa, a);
                *(unsigned*)&bufB[1][n][ub] = pkh(pdv, ad);
                *(unsigned*)&bufB[2][n][ub] = pkh(p2, add);
            } else { pa = a; pdv = ad; p2 = add; }
        }
    }
    __syncthreads();

    const f32x4 bb3a = *(const f32x4*)&b3[(wave * 2 + 0) * 16 + q * 4];
    const f32x4 bb3b = *(const f32x4*)&b3[(wave * 2 + 1) * 16 + q * 4];
    const f32x4 w4a  = *(const f32x4*)&W4[(wave * 2 + 0) * 16 + q * 4];
    const f32x4 w4b  = *(const f32x4*)&W4[(wave * 2 + 1) * 16 + q * 4];

    // ---------------- s4: L3e(A)+W4 dot [VALU] + L3k(B) [MFMA, W3 regs reused] ----------------
    {
        #pragma unroll
        for (int s = 0; s < 3; ++s) {
            accB[s][0] = (f32x4){0.f, 0.f, 0.f, 0.f};
            accB[s][1] = (f32x4){0.f, 0.f, 0.f, 0.f};
        }
        float pd0 = 0.f, pd1 = 0.f, pd2 = 0.f;
        #pragma unroll
        for (int c = 0; c < 8; ++c) {
            const half8 f0 = *(const half8*)&bufB[0][n][c * 32 + q8];
            const half8 f1 = *(const half8*)&bufB[1][n][c * 32 + q8];
            const half8 f2 = *(const half8*)&bufB[2][n][c * 32 + q8];
            accB[0][0] = MFMA16(wc[0][c], f0, accB[0][0]);
            accB[1][0] = MFMA16(wc[0][c], f1, accB[1][0]);
            accB[2][0] = MFMA16(wc[0][c], f2, accB[2][0]);
            accB[0][1] = MFMA16(wc[1][c], f0, accB[0][1]);
            accB[1][1] = MFMA16(wc[1][c], f1, accB[1][1]);
            accB[2][1] = MFMA16(wc[1][c], f2, accB[2][1]);
            // L3e(A) fused with W4 dot, e=c
            const int t = c >> 2, r = c & 3;
            const float z   = accA[0][t][r] + ((c < 4) ? bb3a[r] : bb3b[r]);
            const float a   = fast_tanh(z);
            const float sN  = fmaf(-a, a, 1.0f);
            const float zd  = accA[1][t][r];
            const float zdd = accA[2][t][r];
            const float ad  = sN * zd;
            const float tt  = a * ad * zd;
            const float add = fmaf(sN, zdd, -2.0f * tt);
            const float w4v = (c < 4) ? w4a[r] : w4b[r];
            pd0 = fmaf(a,   w4v, pd0);
            pd1 = fmaf(ad,  w4v, pd1);
            pd2 = fmaf(add, w4v, pd2);
        }
        pd0 += __shfl_xor(pd0, 16, 64); pd0 += __shfl_xor(pd0, 32, 64);
        pd1 += __shfl_xor(pd1, 16, 64); pd1 += __shfl_xor(pd1, 32, 64);
        pd2 += __shfl_xor(pd2, 16, 64); pd2 += __shfl_xor(pd2, 32, 64);
        if (lane < 16) {              // psumA aliases bufA (dead since s3)
            psumA[(wave * 3 + 0) * 16 + lane] = pd0;
            psumA[(wave * 3 + 1) * 16 + lane] = pd1;
            psumA[(wave * 3 + 2) * 16 + lane] = pd2;
        }
    }
    __syncthreads();

    // ---------------- s5: L3e(B)+W4 dot [VALU], outputs ----------------
    {
        float pd0 = 0.f, pd1 = 0.f, pd2 = 0.f;
        #pragma unroll
        for (int c = 0; c < 8; ++c) {
            const int t = c >> 2, r = c & 3;
            const float z   = accB[0][t][r] + ((c < 4) ? bb3a[r] : bb3b[r]);
            const float a   = fast_tanh(z);
            const float sN  = fmaf(-a, a, 1.0f);
            const float zd  = accB[1][t][r];
            const float zdd = accB[2][t][r];
            const float ad  = sN * zd;
            const float tt  = a * ad * zd;
            const float add = fmaf(sN, zdd, -2.0f * tt);
            const float w4v = (c < 4) ? w4a[r] : w4b[r];
            pd0 = fmaf(a,   w4v, pd0);
            pd1 = fmaf(ad,  w4v, pd1);
            pd2 = fmaf(add, w4v, pd2);
        }
        pd0 += __shfl_xor(pd0, 16, 64); pd0 += __shfl_xor(pd0, 32, 64);
        pd1 += __shfl_xor(pd1, 16, 64); pd1 += __shfl_xor(pd1, 32, 64);
        pd2 += __shfl_xor(pd2, 16, 64); pd2 += __shfl_xor(pd2, 32, 64);
        if (lane < 16) {              // psumB aliases bufB (dead after s4)
            psumB[(wave * 3 + 0) * 16 + lane] = pd0;
            psumB[(wave * 3 + 1) * 16 + lane] = pd1;
            psumB[(wave * 3 + 2) * 16 + lane] = pd2;
        }
    }
    __syncthreads();

    if (tid < 96) {
        const int s  = tid >> 5;          // 0:u 1:du 2:d2u
        const int m  = tid & 31;          // 0..15 tile A, 16..31 tile B
        const float* ps = (m & 16) ? psumB : psumA;
        const int nn = m & 15;
        float v = 0.f;
        #pragma unroll
        for (int w = 0; w < 8; ++w) v += ps[(w * 3 + s) * 16 + nn];
        if (s == 0) v += b4[0];
        out[(size_t)s * B + sA + m] = v;
    }
    #undef WIDX
}

extern "C" void kernel_launch(void* const* d_in, const int* in_sizes, int n_in,
                              void* d_out, int out_size, void* d_ws, size_t ws_size,
                              hipStream_t stream) {
    const float* x  = (const float*)d_in[0];
    const float* W1 = (const float*)d_in[1];
    const float* b1 = (const float*)d_in[2];
    const float* W2 = (const float*)d_in[3];
    const float* b2 = (const float*)d_in[4];
    const float* W3 = (const float*)d_in[5];
    const float* b3 = (const float*)d_in[6];
    const float* W4 = (const float*)d_in[7];
    const float* b4 = (const float*)d_in[8];
    float* out = (float*)d_out;

    const int B = in_sizes[0] / 2;      // x is (B, 2)

    prep_w<<<64, 256, 0, stream>>>(W2, W3, (_Float16*)d_ws);
    pinn_mfma<<<B / 32, 512, 0, stream>>>(x, W1, b1, b2, b3, W4, b4,
                                          (const _Float16*)d_ws, out, B);
}

// Round 12
// 191.859 us; speedup vs baseline: 1.0388x; 1.0388x over previous
//
#include <hip/hip_runtime.h>

// PINN fused: u, du/dx0, d2u/dx0^2 of tanh-MLP (2->256->256->256->1), fp32 in/out.
// Round 12: round-8 dataflow (wave-owned 32-unit strips, 32x32x16 MFMA, single
// in-place LDS activation buffer, fused W4 epilogue) with ALL inter-layer
// barriers replaced by fine-grained flags:
//   - produced-flags pr1/pr2[strip]: release after strip written, acquire before read
//   - read-counters rd1[pair]: each wave release-increments after consuming a
//     k-pair; a wave overwrites its own pair only when rd1[pair]==8
//   - k-loops rotated (wave w starts at pair w+1) so its own pair is read last
//   => no __syncthreads between L1 and the final psum reduction; waves drift,
//   one wave's tanh-epilogue VALU overlaps other waves' MFMA k-loops.
// Round-11 lesson applied: keep combined VGPR+AGPR near round 8's (~96) to
// hold 16 waves/CU.

#define HID 256
#define TM  32
#define LDK 264   // f16 row stride (528 B): 4-way max bank aliasing on frag reads

typedef _Float16 half8 __attribute__((ext_vector_type(8)));
typedef _Float16 half4 __attribute__((ext_vector_type(4)));
typedef float    f32x4  __attribute__((ext_vector_type(4)));
typedef float    f32x16 __attribute__((ext_vector_type(16)));

__device__ __forceinline__ float fast_tanh(float z) {
    const float e = __expf(2.0f * z);
#if __has_builtin(__builtin_amdgcn_rcpf)
    const float r = __builtin_amdgcn_rcpf(e + 1.0f);
#else
    const float r = 1.0f / (e + 1.0f);
#endif
    return fmaf(-2.0f, r, 1.0f);
}

__device__ __forceinline__ void flag_set(int* f) {
    __hip_atomic_store(f, 1, __ATOMIC_RELEASE, __HIP_MEMORY_SCOPE_WORKGROUP);
}
__device__ __forceinline__ void flag_wait(int* f) {
    while (__hip_atomic_load(f, __ATOMIC_ACQUIRE, __HIP_MEMORY_SCOPE_WORKGROUP) == 0)
        __builtin_amdgcn_s_sleep(1);
}
__device__ __forceinline__ void cnt_inc(int* c) {
    __hip_atomic_fetch_add(c, 1, __ATOMIC_RELEASE, __HIP_MEMORY_SCOPE_WORKGROUP);
}
__device__ __forceinline__ void cnt_wait8(int* c) {
    while (__hip_atomic_load(c, __ATOMIC_ACQUIRE, __HIP_MEMORY_SCOPE_WORKGROUP) < 8)
        __builtin_amdgcn_s_sleep(1);
}

// Pack W2/W3 (fp32 [256][256], row=k, col=n) into 32x32x16 A-fragment order for
// W^T, fp16. A[m][k]: m = strip*32 + (lane&31), k = c*16 + (lane>>5)*8 + j.
// ws layout (f16 elems): W2 @ 0, W3 @ 65536.  idx = ((strip*16+c)*64+lane)*8+j.
__global__ __launch_bounds__(256) void prep_w(const float* __restrict__ W2,
                                              const float* __restrict__ W3,
                                              _Float16* __restrict__ wsf) {
    const int t = blockIdx.x * 256 + threadIdx.x;     // 0..16383
    const float* __restrict__ W = (t >> 13) ? W3 : W2;
    _Float16* dst = wsf + (size_t)(t >> 13) * 65536;
    const int r    = t & 8191;
    const int s    = r >> 10;          // strip 0..7
    const int c    = (r >> 6) & 15;    // k-chunk 0..15
    const int lane = r & 63;
    const int row0 = c * 16 + ((lane >> 5) << 3);     // k
    const int col  = s * 32 + (lane & 31);            // unit (m)
    half8 vh;
    #pragma unroll
    for (int j = 0; j < 8; ++j)
        vh[j] = (_Float16)W[(size_t)(row0 + j) * HID + col];
    *(half8*)&dst[(size_t)r * 8] = vh;
}

__global__ __launch_bounds__(512) void pinn_mfma(
    const float* __restrict__ x,
    const float* __restrict__ W1, const float* __restrict__ b1,
    const float* __restrict__ b2, const float* __restrict__ b3,
    const float* __restrict__ W4, const float* __restrict__ b4,
    const _Float16* __restrict__ wsf,
    float* __restrict__ out, int B)
{
    __shared__ __align__(16) _Float16 buf[3][TM][LDK];   // 50,688 B
    __shared__ float psum[8][3][TM];                     // 3,072 B
    __shared__ int pr1[8], rd1[8], pr2[8];               // flags/counters

    const int tid  = threadIdx.x;
    const int s0   = blockIdx.x * TM;
    const int lane = tid & 63;
    const int wave = tid >> 6;          // 0..7 = unit strip
    const int n    = lane & 31;         // sample within tile / frag col
    const int q    = lane >> 5;         // k half / unit sub-strip
    const int q8   = q * 8;

    if (tid < 8) { pr1[tid] = 0; rd1[tid] = 0; pr2[tid] = 0; }
    __syncthreads();                    // flags visible before any spin

    // ---------- Layer 1: wave w produces strip w (units 32w..32w+31, all samples) ----------
    {
        const int u0 = wave * 32 + q * 16;            // 16 units for this lane
        const float2 xv = *(const float2*)&x[(size_t)(s0 + n) * 2];
        #pragma unroll
        for (int g = 0; g < 4; ++g) {
            const f32x4 wa = *(const f32x4*)&W1[u0 + g * 4];          // W1[0][u] = z1'
            const f32x4 wb = *(const f32x4*)&W1[HID + u0 + g * 4];
            const f32x4 bv = *(const f32x4*)&b1[u0 + g * 4];
            half4 h0, h1, h2;
            #pragma unroll
            for (int r = 0; r < 4; ++r) {
                const float z  = fmaf(xv.x, wa[r], fmaf(xv.y, wb[r], bv[r]));
                const float a  = fast_tanh(z);
                const float sN = 1.0f - a * a;
                const float ad  = sN * wa[r];
                const float add = -2.0f * a * ad * wa[r];
                h0[r] = (_Float16)a;
                h1[r] = (_Float16)ad;
                h2[r] = (_Float16)add;
            }
            *(half4*)&buf[0][n][u0 + g * 4] = h0;
            *(half4*)&buf[1][n][u0 + g * 4] = h1;
            *(half4*)&buf[2][n][u0 + g * 4] = h2;
        }
    }
    if (lane == 0) flag_set(&pr1[wave]);

    f32x16 acc0, acc1, acc2;
    #define WIDX(c) (((size_t)(wave * 16 + (c)) * 64 + lane) * 8)

    // ---------- Layer 2 k-loop: rotated pairs, pr1-gated, rd1-counted ----------
    {
        const _Float16* __restrict__ Wp = wsf;        // W2 pack
        #pragma unroll
        for (int e = 0; e < 16; ++e) { acc0[e] = 0.f; acc1[e] = 0.f; acc2[e] = 0.f; }

        const int p0 = (wave + 1) & 7;
        half8 wA = *(const half8*)&Wp[WIDX(2 * p0)];
        half8 wB = *(const half8*)&Wp[WIDX(2 * p0 + 1)];
        #pragma unroll
        for (int i = 0; i < 8; ++i) {
            const int p = (wave + 1 + i) & 7;
            half8 wAn, wBn;
            if (i < 7) {                // prefetch next pair (independent of flags)
                const int pn = (wave + 2 + i) & 7;
                wAn = *(const half8*)&Wp[WIDX(2 * pn)];
                wBn = *(const half8*)&Wp[WIDX(2 * pn + 1)];
            }
            flag_wait(&pr1[p]);
            {
                const int cc = 2 * p;
                const half8 b0  = *(const half8*)&buf[0][n][cc * 16 + q8];
                const half8 b1f = *(const half8*)&buf[1][n][cc * 16 + q8];
                const half8 b2f = *(const half8*)&buf[2][n][cc * 16 + q8];
                acc0 = __builtin_amdgcn_mfma_f32_32x32x16_f16(wA, b0,  acc0, 0, 0, 0);
                acc1 = __builtin_amdgcn_mfma_f32_32x32x16_f16(wA, b1f, acc1, 0, 0, 0);
                acc2 = __builtin_amdgcn_mfma_f32_32x32x16_f16(wA, b2f, acc2, 0, 0, 0);
            }
            {
                const int cc = 2 * p + 1;
                const half8 b0  = *(const half8*)&buf[0][n][cc * 16 + q8];
                const half8 b1f = *(const half8*)&buf[1][n][cc * 16 + q8];
                const half8 b2f = *(const half8*)&buf[2][n][cc * 16 + q8];
                acc0 = __builtin_amdgcn_mfma_f32_32x32x16_f16(wB, b0,  acc0, 0, 0, 0);
                acc1 = __builtin_amdgcn_mfma_f32_32x32x16_f16(wB, b1f, acc1, 0, 0, 0);
                acc2 = __builtin_amdgcn_mfma_f32_32x32x16_f16(wB, b2f, acc2, 0, 0, 0);
            }
            if (lane == 0) cnt_inc(&rd1[p]);
            wA = wAn; wB = wBn;
        }
    }

    // ---------- Layer 2 epilogue: wait all readers of own pair, overwrite in place ----------
    // D: col = lane&31 = sample, row = (reg&3) + 8*(reg>>2) + 4*q  (+ wave*32)
    {
        float na[16], nd[16], n2[16];
        #pragma unroll
        for (int g = 0; g < 4; ++g) {
            const int ub = wave * 32 + g * 8 + q * 4;
            const f32x4 bb = *(const f32x4*)&b2[ub];
            #pragma unroll
            for (int r = 0; r < 4; ++r) {
                const float z   = acc0[g * 4 + r] + bb[r];
                const float a   = fast_tanh(z);
                const float sN  = 1.0f - a * a;
                const float zd  = acc1[g * 4 + r];
                const float zdd = acc2[g * 4 + r];
                const float ad  = sN * zd;
                const float add = fmaf(sN, zdd, -2.0f * a * ad * zd);
                na[g * 4 + r] = a; nd[g * 4 + r] = ad; n2[g * 4 + r] = add;
            }
        }
        cnt_wait8(&rd1[wave]);          // all 8 waves consumed pair `wave`
        #pragma unroll
        for (int g = 0; g < 4; ++g) {
            const int ub = wave * 32 + g * 8 + q * 4;
            half4 h0, h1, h2;
            #pragma unroll
            for (int r = 0; r < 4; ++r) {
                h0[r] = (_Float16)na[g * 4 + r];
                h1[r] = (_Float16)nd[g * 4 + r];
                h2[r] = (_Float16)n2[g * 4 + r];
            }
            *(half4*)&buf[0][n][ub] = h0;
            *(half4*)&buf[1][n][ub] = h1;
            *(half4*)&buf[2][n][ub] = h2;
        }
    }
    if (lane == 0) flag_set(&pr2[wave]);

    // ---------- Layer 3 k-loop: rotated pairs, pr2-gated (no counters needed) ----------
    {
        const _Float16* __restrict__ Wp = wsf + 65536;   // W3 pack
        #pragma unroll
        for (int e = 0; e < 16; ++e) { acc0[e] = 0.f; acc1[e] = 0.f; acc2[e] = 0.f; }

        const int p0 = (wave + 1) & 7;
        half8 wA = *(const half8*)&Wp[WIDX(2 * p0)];
        half8 wB = *(const half8*)&Wp[WIDX(2 * p0 + 1)];
        #pragma unroll
        for (int i = 0; i < 8; ++i) {
            const int p = (wave + 1 + i) & 7;
            half8 wAn, wBn;
            if (i < 7) {
                const int pn = (wave + 2 + i) & 7;
                wAn = *(const half8*)&Wp[WIDX(2 * pn)];
                wBn = *(const half8*)&Wp[WIDX(2 * pn + 1)];
            }
            flag_wait(&pr2[p]);
            {
                const int cc = 2 * p;
                const half8 b0  = *(const half8*)&buf[0][n][cc * 16 + q8];
                const half8 b1f = *(const half8*)&buf[1][n][cc * 16 + q8];
                const half8 b2f = *(const half8*)&buf[2][n][cc * 16 + q8];
                acc0 = __builtin_amdgcn_mfma_f32_32x32x16_f16(wA, b0,  acc0, 0, 0, 0);
                acc1 = __builtin_amdgcn_mfma_f32_32x32x16_f16(wA, b1f, acc1, 0, 0, 0);
                acc2 = __builtin_amdgcn_mfma_f32_32x32x16_f16(wA, b2f, acc2, 0, 0, 0);
            }
            {
                const int cc = 2 * p + 1;
                const half8 b0  = *(const half8*)&buf[0][n][cc * 16 + q8];
                const half8 b1f = *(const half8*)&buf[1][n][cc * 16 + q8];
                const half8 b2f = *(const half8*)&buf[2][n][cc * 16 + q8];
                acc0 = __builtin_amdgcn_mfma_f32_32x32x16_f16(wB, b0,  acc0, 0, 0, 0);
                acc1 = __builtin_amdgcn_mfma_f32_32x32x16_f16(wB, b1f, acc1, 0, 0, 0);
                acc2 = __builtin_amdgcn_mfma_f32_32x32x16_f16(wB, b2f, acc2, 0, 0, 0);
            }
            wA = wAn; wB = wBn;
        }
    }
    #undef WIDX

    // ---------- Layer 3 epilogue fused with W4 dot (registers only) ----------
    float pd0 = 0.f, pd1 = 0.f, pd2 = 0.f;
    #pragma unroll
    for (int g = 0; g < 4; ++g) {
        const int ub = wave * 32 + g * 8 + q * 4;
        const f32x4 bb = *(const f32x4*)&b3[ub];
        const f32x4 w4 = *(const f32x4*)&W4[ub];
        #pragma unroll
        for (int r = 0; r < 4; ++r) {
            const float z   = acc0[g * 4 + r] + bb[r];
            const float a   = fast_tanh(z);
            const float sN  = 1.0f - a * a;
            const float zd  = acc1[g * 4 + r];
            const float zdd = acc2[g * 4 + r];
            const float ad  = sN * zd;
            const float add = fmaf(sN, zdd, -2.0f * a * ad * zd);
            pd0 = fmaf(a,   w4[r], pd0);
            pd1 = fmaf(ad,  w4[r], pd1);
            pd2 = fmaf(add, w4[r], pd2);
        }
    }
    // lanes n and n+32 hold the two halves of each sample's strip-partial
    pd0 += __shfl_xor(pd0, 32, 64);
    pd1 += __shfl_xor(pd1, 32, 64);
    pd2 += __shfl_xor(pd2, 32, 64);
    if (lane < 32) {
        psum[wave][0][lane] = pd0;
        psum[wave][1][lane] = pd1;
        psum[wave][2][lane] = pd2;
    }
    __syncthreads();                    // only remaining block-wide barrier

    if (tid < 96) {
        const int s = tid >> 5;          // 0:u 1:du 2:d2u
        const int m = tid & 31;
        float v = 0.f;
        #pragma unroll
        for (int w = 0; w < 8; ++w) v += psum[w][s][m];
        if (s == 0) v += b4[0];
        out[(size_t)s * B + s0 + m] = v;
    }
}

extern "C" void kernel_launch(void* const* d_in, const int* in_sizes, int n_in,
                              void* d_out, int out_size, void* d_ws, size_t ws_size,
                              hipStream_t stream) {
    const float* x  = (const float*)d_in[0];
    const float* W1 = (const float*)d_in[1];
    const float* b1 = (const float*)d_in[2];
    const float* W2 = (const float*)d_in[3];
    const float* b2 = (const float*)d_in[4];
    const float* W3 = (const float*)d_in[5];
    const float* b3 = (const float*)d_in[6];
    const float* W4 = (const float*)d_in[7];
    const float* b4 = (const float*)d_in[8];
    float* out = (float*)d_out;

    const int B = in_sizes[0] / 2;      // x is (B, 2)

    prep_w<<<64, 256, 0, stream>>>(W2, W3, (_Float16*)d_ws);
    pinn_mfma<<<B / TM, 512, 0, stream>>>(x, W1, b1, b2, b3, W4, b4,
                                          (const _Float16*)d_ws, out, B);
}